// Round 2
// baseline (131.099 us; speedup 1.0000x reference)
//
#include <hip/hip_runtime.h>
#include <math.h>

// ---------------------------------------------------------------------------
// Single-kernel Refiner (plus one tiny memset graph node for the barrier).
//
// Algebra: feature channels enter each stage linearly through bilinear
// resize, so pre-reduce B[s][t][u][v] = sum_c conv_w[1+c][t] * f14[s][c][u][v]
// (9 taps x 14x14 per stage). Each stage's 768-channel feature term becomes
// one bilinear sample of B. BN is affine => commutes with bilinear upsample,
// so the h-upsample fuses into the consumer's sampling.
//
// Structure: phase 0 distributes B (784 rows / 112 blocks) + W-transpose
// across the grid; ONE device-scope grid barrier; then every block
// recomputes stages 1-3 redundantly in LDS (cheap: ~37K taps), computes the
// 3 y4 rows its 2 output rows depend on, and does the fused
// up2 + Linear(224,224) + sigmoid for output rows 2b, 2b+1.
//
// Barrier safety: grid = 112 blocks x 256 thr (<= 1 block/CU on 256 CUs) so
// all blocks are co-resident; counter is zeroed by hipMemsetAsync each call;
// device-scope acq/rel atomics + __threadfence handle cross-XCD visibility.
// ---------------------------------------------------------------------------

#define BN_EPS 1e-5f
#define GRID 112

__device__ __forceinline__ float clampf(float x, float lo, float hi) {
    return fminf(fmaxf(x, lo), hi);
}

// Bilinear sample of one 14x14 tap-plane of B (already clamped coords).
__device__ __forceinline__ float sampleB(const float* __restrict__ Bt, float fy, float fx) {
    int y0 = (int)fy; float by = fy - (float)y0; int y1 = min(y0 + 1, 13);
    int x0 = (int)fx; float bx = fx - (float)x0; int x1 = min(x0 + 1, 13);
    return (1.f - by) * ((1.f - bx) * Bt[y0 * 14 + x0] + bx * Bt[y0 * 14 + x1])
         + by         * ((1.f - bx) * Bt[y1 * 14 + x0] + bx * Bt[y1 * 14 + x1]);
}

// Conv accumulator (pre-ReLU/BN) for one output pixel of a stage at
// resolution H. hsrc at srcH; doUp=1 -> sample hsrc with 2x bilinear up.
__device__ __forceinline__ float stage_pixel(int i, int j, int H,
                                             const float* __restrict__ hsrc, int srcH, int doUp,
                                             const float* __restrict__ sB,  // 9*196 this stage
                                             const float* __restrict__ cw, float bias) {
    float featScale = 14.0f / (float)H;
    float srcMax = (float)(srcH - 1);
    float acc = bias;

#pragma unroll
    for (int a = 0; a < 3; ++a) {
        int p = i + a - 1;
        if (p < 0 || p >= H) continue;          // SAME zero padding
        float fy = clampf(((float)p + 0.5f) * featScale - 0.5f, 0.f, 13.f);
        float hy = 0.f; int hy0 = 0, hy1 = 0; float fhy = 0.f;
        if (doUp) {
            hy = clampf(((float)p + 0.5f) * 0.5f - 0.5f, 0.f, srcMax);
            hy0 = (int)hy; fhy = hy - (float)hy0; hy1 = min(hy0 + 1, srcH - 1);
        }
#pragma unroll
        for (int bq = 0; bq < 3; ++bq) {
            int q = j + bq - 1;
            if (q < 0 || q >= H) continue;
            int t = a * 3 + bq;

            float fx = clampf(((float)q + 0.5f) * featScale - 0.5f, 0.f, 13.f);
            float bv = sampleB(sB + t * 196, fy, fx);

            float hval;
            if (doUp) {
                float hx = clampf(((float)q + 0.5f) * 0.5f - 0.5f, 0.f, srcMax);
                int hx0 = (int)hx; float fhx = hx - (float)hx0; int hx1 = min(hx0 + 1, srcH - 1);
                hval = (1.f - fhy) * ((1.f - fhx) * hsrc[hy0 * srcH + hx0] + fhx * hsrc[hy0 * srcH + hx1])
                     + fhy         * ((1.f - fhx) * hsrc[hy1 * srcH + hx0] + fhx * hsrc[hy1 * srcH + hx1]);
            } else {
                hval = hsrc[p * srcH + q];
            }
            acc += cw[t] * hval + bv;
        }
    }
    return acc;
}

__global__ __launch_bounds__(256, 1)
void fused_refiner_kernel(const float* __restrict__ x, const float* __restrict__ fv,
                          const float* __restrict__ conv_w, const float* __restrict__ conv_b,
                          const float* __restrict__ bng, const float* __restrict__ bnb,
                          const float* __restrict__ bnm, const float* __restrict__ bnv,
                          const float* __restrict__ W_w, const float* __restrict__ W_b,
                          float* __restrict__ out,
                          float* __restrict__ gB, float* __restrict__ gWT,
                          unsigned* __restrict__ bar) {
    __shared__ float sB[4 * 9 * 196];   // 28224 B
    __shared__ float y1s[196];
    __shared__ float y2s[784];
    __shared__ float y3s[3136];
    __shared__ float y4loc[3 * 112];    // rows b-1, b, b+1
    __shared__ float hrow[2][224];
    __shared__ float red[4][9];

    int tid = threadIdx.x;
    int b = blockIdx.x;

    // ---- Phase 0a: this block's 7 rows of B -> global gB ----
    for (int r = b * 7; r < b * 7 + 7; ++r) {
        int s = r / 196, uv = r % 196;
        int fidx = 3 - s;
        const float* fvrow = fv + ((size_t)fidx * 197 + 1 + uv) * 768;

        float part[9];
#pragma unroll
        for (int t = 0; t < 9; ++t) part[t] = 0.f;
        for (int k = tid; k < 768; k += 256) {
            float fval = fvrow[k];
            const float* w = conv_w + (size_t)(1 + k) * 9;
#pragma unroll
            for (int t = 0; t < 9; ++t) part[t] += fval * w[t];
        }
#pragma unroll
        for (int t = 0; t < 9; ++t) {
#pragma unroll
            for (int off = 32; off > 0; off >>= 1)
                part[t] += __shfl_down(part[t], off, 64);
        }
        int wave = tid >> 6, lane = tid & 63;
        if (lane == 0) {
#pragma unroll
            for (int t = 0; t < 9; ++t) red[wave][t] = part[t];
        }
        __syncthreads();
        if (tid < 9)
            gB[s * 1764 + tid * 196 + uv] = red[0][tid] + red[1][tid] + red[2][tid] + red[3][tid];
        __syncthreads();
    }

    // ---- Phase 0b: W transpose (WT[w*224+o] = W[o*224+w]) ----
    for (int idx = b * 256 + tid; idx < 224 * 224; idx += GRID * 256) {
        int w = idx / 224, o = idx % 224;
        gWT[idx] = W_w[o * 224 + w];
    }

    // ---- Grid barrier (device scope; counter zeroed by memset node) ----
    __syncthreads();
    if (tid == 0) {
        __threadfence();
        __hip_atomic_fetch_add(bar, 1u, __ATOMIC_ACQ_REL, __HIP_MEMORY_SCOPE_AGENT);
        while (__hip_atomic_load(bar, __ATOMIC_ACQUIRE, __HIP_MEMORY_SCOPE_AGENT) < (unsigned)GRID)
            __builtin_amdgcn_s_sleep(1);
    }
    __syncthreads();

    // ---- Load all of B into LDS; uniform params into regs ----
    for (int k = tid; k < 7056; k += 256) sB[k] = gB[k];

    float cw[9];
#pragma unroll
    for (int t = 0; t < 9; ++t) cw[t] = conv_w[t];   // channel 0 (h) weights
    float bias = conv_b[0];
    float scale = bng[0] * rsqrtf(bnv[0] + BN_EPS);
    float shift = bnb[0] - bnm[0] * scale;
    __syncthreads();

    // ---- Stage 1 (H=14, h = x directly) ----
    for (int px = tid; px < 196; px += 256) {
        int i = px / 14, j = px % 14;
        float acc = stage_pixel(i, j, 14, x, 14, 0, sB, cw, bias);
        y1s[px] = fmaxf(acc, 0.f) * scale + shift;
    }
    __syncthreads();

    // ---- Stage 2 (H=28, h = up2(y1)) ----
    for (int px = tid; px < 784; px += 256) {
        int i = px / 28, j = px % 28;
        float acc = stage_pixel(i, j, 28, y1s, 14, 1, sB + 1764, cw, bias);
        y2s[px] = fmaxf(acc, 0.f) * scale + shift;
    }
    __syncthreads();

    // ---- Stage 3 (H=56) ----
    for (int px = tid; px < 3136; px += 256) {
        int i = px / 56, j = px % 56;
        float acc = stage_pixel(i, j, 56, y2s, 28, 1, sB + 2 * 1764, cw, bias);
        y3s[px] = fmaxf(acc, 0.f) * scale + shift;
    }
    __syncthreads();

    // ---- Stage 4: only rows b-1, b, b+1 (what output rows 2b,2b+1 need) ----
    for (int t2 = tid; t2 < 3 * 112; t2 += 256) {
        int rr = t2 / 112, j = t2 % 112;
        int i = b - 1 + rr;
        if (i >= 0 && i < 112) {
            float acc = stage_pixel(i, j, 112, y3s, 56, 1, sB + 3 * 1764, cw, bias);
            y4loc[rr * 112 + j] = fmaxf(acc, 0.f) * scale + shift;
        }
    }
    __syncthreads();

    // ---- up2(y4) rows 2b, 2b+1 -> hrow ----
    for (int k = tid; k < 2 * 224; k += 256) {
        int rr = k / 224, w = k % 224;
        int r = 2 * b + rr;
        float hy = clampf(((float)r + 0.5f) * 0.5f - 0.5f, 0.f, 111.f);
        int yy0 = (int)hy; float fy = hy - (float)yy0; int yy1 = min(yy0 + 1, 111);
        float hx = clampf(((float)w + 0.5f) * 0.5f - 0.5f, 0.f, 111.f);
        int xx0 = (int)hx; float fx = hx - (float)xx0; int xx1 = min(xx0 + 1, 111);
        int s0 = yy0 - (b - 1), s1 = yy1 - (b - 1);  // local slots in y4loc
        hrow[rr][w] = (1.f - fy) * ((1.f - fx) * y4loc[s0 * 112 + xx0] + fx * y4loc[s0 * 112 + xx1])
                    + fy         * ((1.f - fx) * y4loc[s1 * 112 + xx0] + fx * y4loc[s1 * 112 + xx1]);
    }
    __syncthreads();

    // ---- Linear(224,224) + bias + sigmoid for rows 2b, 2b+1 ----
    int o = tid;
    if (o < 224) {
        float wb = W_b[o];
        float a0 = wb, a1 = wb;
        for (int w = 0; w < 224; ++w) {
            float wt = gWT[w * 224 + o];   // coalesced across threads
            a0 += hrow[0][w] * wt;
            a1 += hrow[1][w] * wt;
        }
        out[(size_t)(2 * b) * 224 + o]     = 1.f / (1.f + expf(-a0));
        out[(size_t)(2 * b + 1) * 224 + o] = 1.f / (1.f + expf(-a1));
    }
}

extern "C" void kernel_launch(void* const* d_in, const int* in_sizes, int n_in,
                              void* d_out, int out_size, void* d_ws, size_t ws_size,
                              hipStream_t stream) {
    (void)in_sizes; (void)n_in; (void)out_size; (void)ws_size;
    const float* x      = (const float*)d_in[0];
    const float* fv     = (const float*)d_in[1];
    const float* conv_w = (const float*)d_in[2];
    const float* conv_b = (const float*)d_in[3];
    const float* bng    = (const float*)d_in[4];
    const float* bnb    = (const float*)d_in[5];
    const float* bnm    = (const float*)d_in[6];
    const float* bnv    = (const float*)d_in[7];
    const float* W_w    = (const float*)d_in[8];
    const float* W_b    = (const float*)d_in[9];
    float* out = (float*)d_out;

    float* ws = (float*)d_ws;
    float*    gB  = ws;                       // 7056 floats
    float*    gWT = ws + 7056;                // 50176 floats
    unsigned* bar = (unsigned*)(ws + 7056 + 50176);  // 64B-aligned (228928 % 64 == 0)

    hipMemsetAsync((void*)bar, 0, 64, stream);
    fused_refiner_kernel<<<GRID, 256, 0, stream>>>(x, fv, conv_w, conv_b,
                                                   bng, bnb, bnm, bnv,
                                                   W_w, W_b, out, gB, gWT, bar);
}

// Round 3
// 117.579 us; speedup vs baseline: 1.1150x; 1.1150x over previous
//
#include <hip/hip_runtime.h>
#include <math.h>

// ---------------------------------------------------------------------------
// Single-kernel Refiner (one memset node for the grid-barrier counter).
//
// Algebra: feature channels enter each stage linearly through bilinear
// resize, so pre-reduce B[s][t][u][v] = sum_c conv_w[1+c][t] * f14[s][c][u][v]
// (9 taps x 14x14 per stage). Each stage's 768-channel feature term becomes
// one bilinear sample of B. BN is affine => commutes with bilinear upsample,
// so the h-upsample fuses into the consumer's sampling.
//
// R3: 1024 thr/block (4 waves/SIMD -> latency hiding), per-wave B dot
// products, coalesced-read transpose, split final matmul.
// Grid barrier: 112 blocks <= capacity (51KB LDS -> 2+ blocks/CU), counter
// zeroed by memset node, relaxed spin + acquire confirm.
// ---------------------------------------------------------------------------

#define BN_EPS 1e-5f
#define GRID 112

__device__ __forceinline__ float clampf(float x, float lo, float hi) {
    return fminf(fmaxf(x, lo), hi);
}

__device__ __forceinline__ float sampleB(const float* __restrict__ Bt, float fy, float fx) {
    int y0 = (int)fy; float by = fy - (float)y0; int y1 = min(y0 + 1, 13);
    int x0 = (int)fx; float bx = fx - (float)x0; int x1 = min(x0 + 1, 13);
    return (1.f - by) * ((1.f - bx) * Bt[y0 * 14 + x0] + bx * Bt[y0 * 14 + x1])
         + by         * ((1.f - bx) * Bt[y1 * 14 + x0] + bx * Bt[y1 * 14 + x1]);
}

// Conv accumulator (pre-ReLU/BN) for one pixel at resolution H.
__device__ __forceinline__ float stage_pixel(int i, int j, int H,
                                             const float* __restrict__ hsrc, int srcH, int doUp,
                                             const float* __restrict__ sB,
                                             const float* __restrict__ cw, float bias) {
    float featScale = 14.0f / (float)H;
    float srcMax = (float)(srcH - 1);
    float acc = bias;

#pragma unroll
    for (int a = 0; a < 3; ++a) {
        int p = i + a - 1;
        if (p < 0 || p >= H) continue;          // SAME zero padding
        float fy = clampf(((float)p + 0.5f) * featScale - 0.5f, 0.f, 13.f);
        int hy0 = 0, hy1 = 0; float fhy = 0.f;
        if (doUp) {
            float hy = clampf(((float)p + 0.5f) * 0.5f - 0.5f, 0.f, srcMax);
            hy0 = (int)hy; fhy = hy - (float)hy0; hy1 = min(hy0 + 1, srcH - 1);
        }
#pragma unroll
        for (int bq = 0; bq < 3; ++bq) {
            int q = j + bq - 1;
            if (q < 0 || q >= H) continue;
            int t = a * 3 + bq;

            float fx = clampf(((float)q + 0.5f) * featScale - 0.5f, 0.f, 13.f);
            float bv = sampleB(sB + t * 196, fy, fx);

            float hval;
            if (doUp) {
                float hx = clampf(((float)q + 0.5f) * 0.5f - 0.5f, 0.f, srcMax);
                int hx0 = (int)hx; float fhx = hx - (float)hx0; int hx1 = min(hx0 + 1, srcH - 1);
                hval = (1.f - fhy) * ((1.f - fhx) * hsrc[hy0 * srcH + hx0] + fhx * hsrc[hy0 * srcH + hx1])
                     + fhy         * ((1.f - fhx) * hsrc[hy1 * srcH + hx0] + fhx * hsrc[hy1 * srcH + hx1]);
            } else {
                hval = hsrc[p * srcH + q];
            }
            acc += cw[t] * hval + bv;
        }
    }
    return acc;
}

__global__ __launch_bounds__(1024, 1)
void fused_refiner_kernel(const float* __restrict__ x, const float* __restrict__ fv,
                          const float* __restrict__ conv_w, const float* __restrict__ conv_b,
                          const float* __restrict__ bng, const float* __restrict__ bnb,
                          const float* __restrict__ bnm, const float* __restrict__ bnv,
                          const float* __restrict__ W_w, const float* __restrict__ W_b,
                          float* __restrict__ out,
                          float* __restrict__ gB, float* __restrict__ gWT,
                          unsigned* __restrict__ bar) {
    __shared__ float sB[4 * 9 * 196];     // 28224 B
    __shared__ float y1s[196];
    __shared__ float y2s[784];
    __shared__ float y3s[3136];
    __shared__ float y4loc[3 * 112];
    __shared__ float hrow[2][224];
    __shared__ float partial[4][224];     // total ~51.4 KB

    int tid = threadIdx.x;
    int b = blockIdx.x;
    int wave = tid >> 6, lane = tid & 63;

    // ---- Phase 0a: B rows for this block, one (row,tap) unit per wave ----
    // Block b owns rows [b*7, b*7+7); 7 rows x 9 taps = 63 units / 16 waves.
#pragma unroll
    for (int i = 0; i < 4; ++i) {
        int u = wave + 16 * i;
        if (u < 63) {
            int lr = u / 9, t = u % 9;
            int r = b * 7 + lr;
            int s = r / 196, uv = r % 196;
            const float* fvrow = fv + ((size_t)(3 - s) * 197 + 1 + uv) * 768;
            float acc = 0.f;
#pragma unroll
            for (int m = 0; m < 12; ++m) {
                int k = lane + 64 * m;
                acc += fvrow[k] * conv_w[(size_t)(1 + k) * 9 + t];
            }
#pragma unroll
            for (int off = 32; off > 0; off >>= 1)
                acc += __shfl_down(acc, off, 64);
            if (lane == 0) gB[s * 1764 + t * 196 + uv] = acc;
        }
    }

    // ---- Phase 0b: W transpose, coalesced reads / scattered writes ----
    {
        int idx = b * 1024 + tid;
        if (idx < 224 * 224) {
            int o = idx / 224, w = idx % 224;   // read W_w coalesced
            gWT[w * 224 + o] = W_w[idx];
        }
    }

    // ---- Grid barrier ----
    __syncthreads();
    if (tid == 0) {
        __threadfence();
        __hip_atomic_fetch_add(bar, 1u, __ATOMIC_ACQ_REL, __HIP_MEMORY_SCOPE_AGENT);
        while (__hip_atomic_load(bar, __ATOMIC_RELAXED, __HIP_MEMORY_SCOPE_AGENT) < (unsigned)GRID)
            __builtin_amdgcn_s_sleep(1);
        (void)__hip_atomic_load(bar, __ATOMIC_ACQUIRE, __HIP_MEMORY_SCOPE_AGENT);
    }
    __syncthreads();

    // ---- B -> LDS; uniform params ----
    for (int k = tid; k < 7056; k += 1024) sB[k] = gB[k];

    float cw[9];
#pragma unroll
    for (int t = 0; t < 9; ++t) cw[t] = conv_w[t];
    float bias = conv_b[0];
    float scale = bng[0] * rsqrtf(bnv[0] + BN_EPS);
    float shift = bnb[0] - bnm[0] * scale;
    __syncthreads();

    // ---- Stage 1 (14x14, h = x) ----
    if (tid < 196) {
        int i = tid / 14, j = tid % 14;
        float acc = stage_pixel(i, j, 14, x, 14, 0, sB, cw, bias);
        y1s[tid] = fmaxf(acc, 0.f) * scale + shift;
    }
    __syncthreads();

    // ---- Stage 2 (28x28) ----
    if (tid < 784) {
        int i = tid / 28, j = tid % 28;
        float acc = stage_pixel(i, j, 28, y1s, 14, 1, sB + 1764, cw, bias);
        y2s[tid] = fmaxf(acc, 0.f) * scale + shift;
    }
    __syncthreads();

    // ---- Stage 3 (56x56): 3136 px, ~3 independent px/thread ----
    for (int px = tid; px < 3136; px += 1024) {
        int i = px / 56, j = px % 56;
        float acc = stage_pixel(i, j, 56, y2s, 28, 1, sB + 2 * 1764, cw, bias);
        y3s[px] = fmaxf(acc, 0.f) * scale + shift;
    }
    __syncthreads();

    // ---- Stage 4: rows b-1, b, b+1 only ----
    if (tid < 3 * 112) {
        int rr = tid / 112, j = tid % 112;
        int i = b - 1 + rr;
        if (i >= 0 && i < 112) {
            float acc = stage_pixel(i, j, 112, y3s, 56, 1, sB + 3 * 1764, cw, bias);
            y4loc[rr * 112 + j] = fmaxf(acc, 0.f) * scale + shift;
        }
    }
    __syncthreads();

    // ---- up2(y4) rows 2b, 2b+1 ----
    if (tid < 2 * 224) {
        int rr = tid / 224, w = tid % 224;
        int r = 2 * b + rr;
        float hy = clampf(((float)r + 0.5f) * 0.5f - 0.5f, 0.f, 111.f);
        int yy0 = (int)hy; float fy = hy - (float)yy0; int yy1 = min(yy0 + 1, 111);
        float hx = clampf(((float)w + 0.5f) * 0.5f - 0.5f, 0.f, 111.f);
        int xx0 = (int)hx; float fx = hx - (float)xx0; int xx1 = min(xx0 + 1, 111);
        int s0 = yy0 - (b - 1), s1 = yy1 - (b - 1);
        hrow[rr][w] = (1.f - fy) * ((1.f - fx) * y4loc[s0 * 112 + xx0] + fx * y4loc[s0 * 112 + xx1])
                    + fy         * ((1.f - fx) * y4loc[s1 * 112 + xx0] + fx * y4loc[s1 * 112 + xx1]);
    }
    __syncthreads();

    // ---- Linear(224,224): (rr, o, half) over 896 threads, 112-long K each ----
    if (tid < 896) {
        int q = tid / 224;            // 0..3: rr = q>>1, half = q&1
        int o = tid % 224;
        int rr = q >> 1, half = q & 1;
        float acc = half ? 0.f : W_b[o];
        const float* hr = hrow[rr];
        int w0 = half * 112;
        for (int w = w0; w < w0 + 112; ++w)
            acc += hr[w] * gWT[w * 224 + o];   // coalesced across o
        partial[q][o] = acc;
    }
    __syncthreads();

    if (tid < 448) {
        int rr = tid / 224, o = tid % 224;
        float v = partial[rr * 2][o] + partial[rr * 2 + 1][o];
        out[(size_t)(2 * b + rr) * 224 + o] = 1.f / (1.f + expf(-v));
    }
}

extern "C" void kernel_launch(void* const* d_in, const int* in_sizes, int n_in,
                              void* d_out, int out_size, void* d_ws, size_t ws_size,
                              hipStream_t stream) {
    (void)in_sizes; (void)n_in; (void)out_size; (void)ws_size;
    const float* x      = (const float*)d_in[0];
    const float* fv     = (const float*)d_in[1];
    const float* conv_w = (const float*)d_in[2];
    const float* conv_b = (const float*)d_in[3];
    const float* bng    = (const float*)d_in[4];
    const float* bnb    = (const float*)d_in[5];
    const float* bnm    = (const float*)d_in[6];
    const float* bnv    = (const float*)d_in[7];
    const float* W_w    = (const float*)d_in[8];
    const float* W_b    = (const float*)d_in[9];
    float* out = (float*)d_out;

    float* ws = (float*)d_ws;
    float*    gB  = ws;                              // 7056 floats
    float*    gWT = ws + 7056;                       // 50176 floats
    unsigned* bar = (unsigned*)(ws + 7056 + 50176);  // 64B-aligned

    hipMemsetAsync((void*)bar, 0, 64, stream);
    fused_refiner_kernel<<<GRID, 1024, 0, stream>>>(x, fv, conv_w, conv_b,
                                                    bng, bnb, bnm, bnv,
                                                    W_w, W_b, out, gB, gWT, bar);
}

// Round 4
// 90.149 us; speedup vs baseline: 1.4543x; 1.3043x over previous
//
#include <hip/hip_runtime.h>
#include <math.h>

// ---------------------------------------------------------------------------
// Two-kernel Refiner, no grid barrier.
//
// Algebra: feature channels enter each stage linearly through bilinear
// resize, so pre-reduce B[s][t][u][v] = sum_c conv_w[1+c][t] * f14[s][c][u][v]
// (9 taps x 14x14 per stage). Each stage's 768-channel feature term becomes
// one bilinear sample of B. BN is affine => commutes with bilinear upsample,
// so the h-upsample fuses into the consumer's sampling.
//
// Kernel A: compute gB (784 blocks, one token-pixel each, 9 tap-dots of 768)
//           + fold in the W transpose (64 elements per block, exact cover).
// Kernel B: 112 blocks; each computes ONLY the dependence cone of its two
//           output rows: ~5 rows of y1/y2, ~4 of y3, 3 of y4 (~770 px vs
//           4452 full) -- every stage is a single <=336-thread pass; then
//           fused up2 + Linear(224,224) + sigmoid.
// R3 lesson: the device-scope barrier (agent atomics + L2 invalidation +
// slowest-arrival serialization) cost ~30 us; a CP kernel boundary is ~6 us.
// ---------------------------------------------------------------------------

#define BN_EPS 1e-5f

__device__ __forceinline__ float clampf(float x, float lo, float hi) {
    return fminf(fmaxf(x, lo), hi);
}

__device__ __forceinline__ float sampleB(const float* __restrict__ Bt, float fy, float fx) {
    int y0 = (int)fy; float by = fy - (float)y0; int y1 = min(y0 + 1, 13);
    int x0 = (int)fx; float bx = fx - (float)x0; int x1 = min(x0 + 1, 13);
    return (1.f - by) * ((1.f - bx) * Bt[y0 * 14 + x0] + bx * Bt[y0 * 14 + x1])
         + by         * ((1.f - bx) * Bt[y1 * 14 + x0] + bx * Bt[y1 * 14 + x1]);
}

// Conv accumulator (pre-ReLU/BN) for one pixel at resolution H.
__device__ __forceinline__ float stage_pixel(int i, int j, int H,
                                             const float* __restrict__ hsrc, int srcH, int doUp,
                                             const float* __restrict__ sB,
                                             const float* __restrict__ cw, float bias) {
    float featScale = 14.0f / (float)H;
    float srcMax = (float)(srcH - 1);
    float acc = bias;

#pragma unroll
    for (int a = 0; a < 3; ++a) {
        int p = i + a - 1;
        if (p < 0 || p >= H) continue;          // SAME zero padding
        float fy = clampf(((float)p + 0.5f) * featScale - 0.5f, 0.f, 13.f);
        int hy0 = 0, hy1 = 0; float fhy = 0.f;
        if (doUp) {
            float hy = clampf(((float)p + 0.5f) * 0.5f - 0.5f, 0.f, srcMax);
            hy0 = (int)hy; fhy = hy - (float)hy0; hy1 = min(hy0 + 1, srcH - 1);
        }
#pragma unroll
        for (int bq = 0; bq < 3; ++bq) {
            int q = j + bq - 1;
            if (q < 0 || q >= H) continue;
            int t = a * 3 + bq;

            float fx = clampf(((float)q + 0.5f) * featScale - 0.5f, 0.f, 13.f);
            float bv = sampleB(sB + t * 196, fy, fx);

            float hval;
            if (doUp) {
                float hx = clampf(((float)q + 0.5f) * 0.5f - 0.5f, 0.f, srcMax);
                int hx0 = (int)hx; float fhx = hx - (float)hx0; int hx1 = min(hx0 + 1, srcH - 1);
                hval = (1.f - fhy) * ((1.f - fhx) * hsrc[hy0 * srcH + hx0] + fhx * hsrc[hy0 * srcH + hx1])
                     + fhy         * ((1.f - fhx) * hsrc[hy1 * srcH + hx0] + fhx * hsrc[hy1 * srcH + hx1]);
            } else {
                hval = hsrc[p * srcH + q];
            }
            acc += cw[t] * hval + bv;
        }
    }
    return acc;
}

// src rows needed to compute dst rows [dlo,dhi] of a stage at H=2*srcH
// (conv taps p in [dlo-1,dhi+1], each sampling src rows hy0, hy0+1).
__device__ __forceinline__ void srcRange(int dlo, int dhi, int srcH, int& slo, int& shi) {
    int H = 2 * srcH;
    int p0 = max(dlo - 1, 0), p1 = min(dhi + 1, H - 1);
    float h0 = fmaxf(((float)p0 + 0.5f) * 0.5f - 0.5f, 0.f);
    float h1 = fmaxf(((float)p1 + 0.5f) * 0.5f - 0.5f, 0.f);
    slo = (int)h0;
    shi = min((int)h1 + 1, srcH - 1);
}

// ---- Kernel A: B pre-reduction + W transpose ----
__global__ __launch_bounds__(256)
void compute_B_kernel(const float* __restrict__ fv, const float* __restrict__ conv_w,
                      const float* __restrict__ W_w,
                      float* __restrict__ gB, float* __restrict__ gWT) {
    int blk = blockIdx.x;          // 0..783
    int s = blk / 196;             // stage 0..3
    int uv = blk % 196;
    const float* fvrow = fv + ((size_t)(3 - s) * 197 + 1 + uv) * 768;
    int tid = threadIdx.x;

    // fold W transpose: 784 blocks x 64 elements == 50176 exactly
    if (tid < 64) {
        int idx = blk * 64 + tid;
        int o = idx / 224, w = idx % 224;     // coalesced read
        gWT[w * 224 + o] = W_w[idx];
    }

    float part[9];
#pragma unroll
    for (int t = 0; t < 9; ++t) part[t] = 0.f;
    for (int k = tid; k < 768; k += 256) {
        float fval = fvrow[k];
        const float* w = conv_w + (size_t)(1 + k) * 9;
#pragma unroll
        for (int t = 0; t < 9; ++t) part[t] += fval * w[t];
    }
#pragma unroll
    for (int t = 0; t < 9; ++t) {
#pragma unroll
        for (int off = 32; off > 0; off >>= 1)
            part[t] += __shfl_down(part[t], off, 64);
    }
    __shared__ float red[4][9];
    int wave = tid >> 6, lane = tid & 63;
    if (lane == 0) {
#pragma unroll
        for (int t = 0; t < 9; ++t) red[wave][t] = part[t];
    }
    __syncthreads();
    if (tid < 9)
        gB[s * 1764 + tid * 196 + uv] = red[0][tid] + red[1][tid] + red[2][tid] + red[3][tid];
}

// ---- Kernel B: cone-pruned stages + fused up2 + Linear + sigmoid ----
__global__ __launch_bounds__(1024, 1)
void refine_kernel(const float* __restrict__ x,
                   const float* __restrict__ conv_w, const float* __restrict__ conv_b,
                   const float* __restrict__ bng, const float* __restrict__ bnb,
                   const float* __restrict__ bnm, const float* __restrict__ bnv,
                   const float* __restrict__ W_b,
                   const float* __restrict__ gB, const float* __restrict__ gWT,
                   float* __restrict__ out) {
    __shared__ float sB[4 * 9 * 196];
    __shared__ float y1s[196];
    __shared__ float y2s[784];
    __shared__ float y3s[3136];
    __shared__ float y4loc[3 * 112];
    __shared__ float hrow[2][224];
    __shared__ float partial[4][224];

    int tid = threadIdx.x;
    int b = blockIdx.x;

    // dependence cone of output rows 2b, 2b+1
    int y4lo = max(b - 1, 0), y4hi = min(b + 1, 111);
    int r3lo, r3hi; srcRange(y4lo, y4hi, 56, r3lo, r3hi);
    int r2lo, r2hi; srcRange(r3lo, r3hi, 28, r2lo, r2hi);
    int r1lo, r1hi; srcRange(r2lo, r2hi, 14, r1lo, r1hi);

    // B -> LDS (7 coalesced rounds)
    for (int k = tid; k < 7056; k += 1024) sB[k] = gB[k];

    float cw[9];
#pragma unroll
    for (int t = 0; t < 9; ++t) cw[t] = conv_w[t];
    float bias = conv_b[0];
    float scale = bng[0] * rsqrtf(bnv[0] + BN_EPS);
    float shift = bnb[0] - bnm[0] * scale;
    __syncthreads();

    // Stage 1 (14x14, h = x global): rows r1lo..r1hi  (<= 6*14 = 84 px)
    {
        int n = (r1hi - r1lo + 1) * 14;
        if (tid < n) {
            int i = r1lo + tid / 14, j = tid % 14;
            float acc = stage_pixel(i, j, 14, x, 14, 0, sB, cw, bias);
            y1s[i * 14 + j] = fmaxf(acc, 0.f) * scale + shift;
        }
    }
    __syncthreads();

    // Stage 2 (28x28): rows r2lo..r2hi  (<= 6*28 = 168 px)
    {
        int n = (r2hi - r2lo + 1) * 28;
        if (tid < n) {
            int i = r2lo + tid / 28, j = tid % 28;
            float acc = stage_pixel(i, j, 28, y1s, 14, 1, sB + 1764, cw, bias);
            y2s[i * 28 + j] = fmaxf(acc, 0.f) * scale + shift;
        }
    }
    __syncthreads();

    // Stage 3 (56x56): rows r3lo..r3hi  (<= 5*56 = 280 px)
    {
        int n = (r3hi - r3lo + 1) * 56;
        if (tid < n) {
            int i = r3lo + tid / 56, j = tid % 56;
            float acc = stage_pixel(i, j, 56, y2s, 28, 1, sB + 2 * 1764, cw, bias);
            y3s[i * 56 + j] = fmaxf(acc, 0.f) * scale + shift;
        }
    }
    __syncthreads();

    // Stage 4: rows y4lo..y4hi  (<= 3*112 = 336 px), slot rr = i-(b-1)
    {
        int n = (y4hi - y4lo + 1) * 112;
        if (tid < n) {
            int i = y4lo + tid / 112, j = tid % 112;
            float acc = stage_pixel(i, j, 112, y3s, 56, 1, sB + 3 * 1764, cw, bias);
            y4loc[(i - (b - 1)) * 112 + j] = fmaxf(acc, 0.f) * scale + shift;
        }
    }
    __syncthreads();

    // up2(y4) rows 2b, 2b+1
    if (tid < 2 * 224) {
        int rr = tid / 224, w = tid % 224;
        int r = 2 * b + rr;
        float hy = clampf(((float)r + 0.5f) * 0.5f - 0.5f, 0.f, 111.f);
        int yy0 = (int)hy; float fy = hy - (float)yy0; int yy1 = min(yy0 + 1, 111);
        float hx = clampf(((float)w + 0.5f) * 0.5f - 0.5f, 0.f, 111.f);
        int xx0 = (int)hx; float fx = hx - (float)xx0; int xx1 = min(xx0 + 1, 111);
        int s0 = yy0 - (b - 1), s1 = yy1 - (b - 1);
        hrow[rr][w] = (1.f - fy) * ((1.f - fx) * y4loc[s0 * 112 + xx0] + fx * y4loc[s0 * 112 + xx1])
                    + fy         * ((1.f - fx) * y4loc[s1 * 112 + xx0] + fx * y4loc[s1 * 112 + xx1]);
    }
    __syncthreads();

    // Linear(224,224): (rr, o, half) over 896 threads, K=112 each
    if (tid < 896) {
        int q = tid / 224, o = tid % 224;
        int rr = q >> 1, half = q & 1;
        float acc = half ? 0.f : W_b[o];
        const float* hr = hrow[rr];
        int w0 = half * 112;
        for (int w = w0; w < w0 + 112; ++w)
            acc += hr[w] * gWT[w * 224 + o];   // coalesced across o
        partial[q][o] = acc;
    }
    __syncthreads();

    if (tid < 448) {
        int rr = tid / 224, o = tid % 224;
        float v = partial[rr * 2][o] + partial[rr * 2 + 1][o];
        out[(size_t)(2 * b + rr) * 224 + o] = 1.f / (1.f + expf(-v));
    }
}

extern "C" void kernel_launch(void* const* d_in, const int* in_sizes, int n_in,
                              void* d_out, int out_size, void* d_ws, size_t ws_size,
                              hipStream_t stream) {
    (void)in_sizes; (void)n_in; (void)out_size; (void)ws_size;
    const float* x      = (const float*)d_in[0];
    const float* fv     = (const float*)d_in[1];
    const float* conv_w = (const float*)d_in[2];
    const float* conv_b = (const float*)d_in[3];
    const float* bng    = (const float*)d_in[4];
    const float* bnb    = (const float*)d_in[5];
    const float* bnm    = (const float*)d_in[6];
    const float* bnv    = (const float*)d_in[7];
    const float* W_w    = (const float*)d_in[8];
    const float* W_b    = (const float*)d_in[9];
    float* out = (float*)d_out;

    float* ws  = (float*)d_ws;
    float* gB  = ws;            // 7056 floats
    float* gWT = ws + 7056;     // 50176 floats

    compute_B_kernel<<<784, 256, 0, stream>>>(fv, conv_w, W_w, gB, gWT);
    refine_kernel<<<112, 1024, 0, stream>>>(x, conv_w, conv_b, bng, bnb, bnm, bnv,
                                            W_b, gB, gWT, out);
}

// Round 5
// 85.891 us; speedup vs baseline: 1.5263x; 1.0496x over previous
//
#include <hip/hip_runtime.h>
#include <math.h>

// ---------------------------------------------------------------------------
// Two-kernel Refiner, no grid barrier.
//
// Algebra: feature channels enter each stage linearly through bilinear
// resize, so pre-reduce B[s][t][u][v] = sum_c conv_w[1+c][t] * f14[s][c][u][v].
// Each stage's 768-channel feature term becomes one bilinear sample of B.
// BN is affine => commutes with bilinear upsample, so the h-upsample fuses
// into the consumer's sampling.
//
// R5 additions:
//  - Final up2-x fold into weights: WTfold[xx][o] = sum_w coef(xx,w)*W[o][w]
//    (computed in kernel A); kernel B computes per-y4-row dots D[i][o]
//    (K=112, one weight read feeds 3 FMAs) and lerps D rows (up2-y) at the
//    end. Cuts matmul L2 traffic 4x and drops the hrow phase.
//  - Kernel B loads only the cone rows of B into LDS (~2.3K of 7056 floats).
//  - Stage 1 uses direct integer indexing of B[0] (featScale=1 => bilinear
//    degenerates to a lookup).
// ---------------------------------------------------------------------------

#define BN_EPS 1e-5f

__device__ __forceinline__ float clampf(float x, float lo, float hi) {
    return fminf(fmaxf(x, lo), hi);
}

__device__ __forceinline__ float sampleB(const float* __restrict__ Bt, float fy, float fx) {
    int y0 = (int)fy; float by = fy - (float)y0; int y1 = min(y0 + 1, 13);
    int x0 = (int)fx; float bx = fx - (float)x0; int x1 = min(x0 + 1, 13);
    return (1.f - by) * ((1.f - bx) * Bt[y0 * 14 + x0] + bx * Bt[y0 * 14 + x1])
         + by         * ((1.f - bx) * Bt[y1 * 14 + x0] + bx * Bt[y1 * 14 + x1]);
}

// Conv accumulator (pre-ReLU/BN) for one pixel at resolution H (up-sampled h).
__device__ __forceinline__ float stage_pixel(int i, int j, int H,
                                             const float* __restrict__ hsrc, int srcH,
                                             const float* __restrict__ sB,
                                             const float* __restrict__ cw, float bias) {
    float featScale = 14.0f / (float)H;
    float srcMax = (float)(srcH - 1);
    float acc = bias;

#pragma unroll
    for (int a = 0; a < 3; ++a) {
        int p = i + a - 1;
        if (p < 0 || p >= H) continue;          // SAME zero padding
        float fy = clampf(((float)p + 0.5f) * featScale - 0.5f, 0.f, 13.f);
        float hy = clampf(((float)p + 0.5f) * 0.5f - 0.5f, 0.f, srcMax);
        int hy0 = (int)hy; float fhy = hy - (float)hy0; int hy1 = min(hy0 + 1, srcH - 1);
#pragma unroll
        for (int bq = 0; bq < 3; ++bq) {
            int q = j + bq - 1;
            if (q < 0 || q >= H) continue;
            int t = a * 3 + bq;

            float fx = clampf(((float)q + 0.5f) * featScale - 0.5f, 0.f, 13.f);
            float bv = sampleB(sB + t * 196, fy, fx);

            float hx = clampf(((float)q + 0.5f) * 0.5f - 0.5f, 0.f, srcMax);
            int hx0 = (int)hx; float fhx = hx - (float)hx0; int hx1 = min(hx0 + 1, srcH - 1);
            float hval = (1.f - fhy) * ((1.f - fhx) * hsrc[hy0 * srcH + hx0] + fhx * hsrc[hy0 * srcH + hx1])
                       + fhy         * ((1.f - fhx) * hsrc[hy1 * srcH + hx0] + fhx * hsrc[hy1 * srcH + hx1]);
            acc += cw[t] * hval + bv;
        }
    }
    return acc;
}

// src rows needed to compute dst rows [dlo,dhi] of a stage at H=2*srcH.
__device__ __forceinline__ void srcRange(int dlo, int dhi, int srcH, int& slo, int& shi) {
    int H = 2 * srcH;
    int p0 = max(dlo - 1, 0), p1 = min(dhi + 1, H - 1);
    float h0 = fmaxf(((float)p0 + 0.5f) * 0.5f - 0.5f, 0.f);
    float h1 = fmaxf(((float)p1 + 0.5f) * 0.5f - 0.5f, 0.f);
    slo = (int)h0;
    shi = min((int)h1 + 1, srcH - 1);
}

// B-plane rows of a stage's sB needed for dst rows [dlo,dhi] at resolution H.
__device__ __forceinline__ void bRange(int dlo, int dhi, int H, int& lo, int& hi) {
    float sc = 14.f / (float)H;
    int p0 = max(dlo - 1, 0), p1 = min(dhi + 1, H - 1);
    float f0 = clampf(((float)p0 + 0.5f) * sc - 0.5f, 0.f, 13.f);
    float f1 = clampf(((float)p1 + 0.5f) * sc - 0.5f, 0.f, 13.f);
    lo = (int)f0;
    hi = min((int)f1 + 1, 13);
}

// ---- Kernel A: B pre-reduction + folded (up2-x . W^T) weights ----
__global__ __launch_bounds__(256)
void compute_B_kernel(const float* __restrict__ fv, const float* __restrict__ conv_w,
                      const float* __restrict__ W_w,
                      float* __restrict__ gB, float* __restrict__ gWTf) {
    int blk = blockIdx.x;          // 0..783
    int s = blk / 196;
    int uv = blk % 196;
    const float* fvrow = fv + ((size_t)(3 - s) * 197 + 1 + uv) * 768;
    int tid = threadIdx.x;

    // folded weights: 784 blocks x 32 == 25088 == 112*224 exactly.
    // gWTf[xx*224+o] = sum_w coef(xx,w) * W[o][w], coef from the canonical
    // clamped half-pixel up2-x lerp (each xx gathers from w in [2xx-1,2xx+2]).
    if (tid < 32) {
        int idx = blk * 32 + tid;
        int o = idx % 224, xx = idx / 224;
        float acc = 0.f;
#pragma unroll
        for (int d = -1; d <= 2; ++d) {
            int w = 2 * xx + d;
            if (w < 0 || w > 223) continue;
            float hx = clampf(((float)w + 0.5f) * 0.5f - 0.5f, 0.f, 111.f);
            int xx0 = (int)hx; float fx = hx - (float)xx0; int xx1 = min(xx0 + 1, 111);
            float c = (xx0 == xx ? 1.f - fx : 0.f) + (xx1 == xx ? fx : 0.f);
            acc += c * W_w[o * 224 + w];
        }
        gWTf[xx * 224 + o] = acc;
    }

    float part[9];
#pragma unroll
    for (int t = 0; t < 9; ++t) part[t] = 0.f;
    for (int k = tid; k < 768; k += 256) {
        float fval = fvrow[k];
        const float* w = conv_w + (size_t)(1 + k) * 9;
#pragma unroll
        for (int t = 0; t < 9; ++t) part[t] += fval * w[t];
    }
#pragma unroll
    for (int t = 0; t < 9; ++t) {
#pragma unroll
        for (int off = 32; off > 0; off >>= 1)
            part[t] += __shfl_down(part[t], off, 64);
    }
    __shared__ float red[4][9];
    int wave = tid >> 6, lane = tid & 63;
    if (lane == 0) {
#pragma unroll
        for (int t = 0; t < 9; ++t) red[wave][t] = part[t];
    }
    __syncthreads();
    if (tid < 9)
        gB[s * 1764 + tid * 196 + uv] = red[0][tid] + red[1][tid] + red[2][tid] + red[3][tid];
}

// ---- Kernel B: cone-pruned stages + D-row dots + up2-y lerp + sigmoid ----
__global__ __launch_bounds__(1024, 1)
void refine_kernel(const float* __restrict__ x,
                   const float* __restrict__ conv_w, const float* __restrict__ conv_b,
                   const float* __restrict__ bng, const float* __restrict__ bnb,
                   const float* __restrict__ bnm, const float* __restrict__ bnv,
                   const float* __restrict__ W_b,
                   const float* __restrict__ gB, const float* __restrict__ gWTf,
                   float* __restrict__ out) {
    __shared__ float sB[4 * 9 * 196];
    __shared__ float y1s[196];
    __shared__ float y2s[784];
    __shared__ float y3s[3136];
    __shared__ float y4loc[3 * 112];
    __shared__ float partial[12 * 224];   // (slot i, K-quarter kq) x o

    int tid = threadIdx.x;
    int b = blockIdx.x;

    // dependence cone of output rows 2b, 2b+1
    int y4lo = max(b - 1, 0), y4hi = min(b + 1, 111);
    int r3lo, r3hi; srcRange(y4lo, y4hi, 56, r3lo, r3hi);
    int r2lo, r2hi; srcRange(r3lo, r3hi, 28, r2lo, r2hi);
    int r1lo, r1hi; srcRange(r2lo, r2hi, 14, r1lo, r1hi);

    // B-plane row windows per stage
    int bl0 = max(r1lo - 1, 0), bh0 = min(r1hi + 1, 13);   // stage 1: integer coords
    int bl1, bh1; bRange(r2lo, r2hi, 28, bl1, bh1);
    int bl2, bh2; bRange(r3lo, r3hi, 56, bl2, bh2);
    int bl3, bh3; bRange(y4lo, y4hi, 112, bl3, bh3);

    // cone-only load of sB (contiguous row windows per (stage, tap) plane)
    {
        int bl[4] = {bl0, bl1, bl2, bl3}, bh[4] = {bh0, bh1, bh2, bh3};
#pragma unroll
        for (int s4 = 0; s4 < 4; ++s4) {
            int nrw = (bh[s4] - bl[s4] + 1) * 14;
            int n = 9 * nrw;
            int base = s4 * 1764 + bl[s4] * 14;
            for (int e = tid; e < n; e += 1024) {
                int t = e / nrw, rem = e % nrw;
                int off = base + t * 196 + rem;
                sB[off] = gB[off];
            }
        }
    }

    float cw[9];
#pragma unroll
    for (int t = 0; t < 9; ++t) cw[t] = conv_w[t];
    float bias = conv_b[0];
    float scale = bng[0] * rsqrtf(bnv[0] + BN_EPS);
    float shift = bnb[0] - bnm[0] * scale;
    __syncthreads();

    // Stage 1 (14x14, h = x, B sampled at integer coords -> direct lookup)
    {
        int n = (r1hi - r1lo + 1) * 14;
        if (tid < n) {
            int i = r1lo + tid / 14, j = tid % 14;
            float acc = bias;
#pragma unroll
            for (int a = 0; a < 3; ++a) {
                int p = i + a - 1;
                if (p < 0 || p >= 14) continue;
#pragma unroll
                for (int bq = 0; bq < 3; ++bq) {
                    int q = j + bq - 1;
                    if (q < 0 || q >= 14) continue;
                    int t = a * 3 + bq;
                    acc += cw[t] * x[p * 14 + q] + sB[t * 196 + p * 14 + q];
                }
            }
            y1s[i * 14 + j] = fmaxf(acc, 0.f) * scale + shift;
        }
    }
    __syncthreads();

    // Stage 2 (28x28)
    {
        int n = (r2hi - r2lo + 1) * 28;
        if (tid < n) {
            int i = r2lo + tid / 28, j = tid % 28;
            float acc = stage_pixel(i, j, 28, y1s, 14, sB + 1764, cw, bias);
            y2s[i * 28 + j] = fmaxf(acc, 0.f) * scale + shift;
        }
    }
    __syncthreads();

    // Stage 3 (56x56)
    {
        int n = (r3hi - r3lo + 1) * 56;
        if (tid < n) {
            int i = r3lo + tid / 56, j = tid % 56;
            float acc = stage_pixel(i, j, 56, y2s, 28, sB + 2 * 1764, cw, bias);
            y3s[i * 56 + j] = fmaxf(acc, 0.f) * scale + shift;
        }
    }
    __syncthreads();

    // Stage 4: rows y4lo..y4hi, slot rr = i-(b-1)
    {
        int n = (y4hi - y4lo + 1) * 112;
        if (tid < n) {
            int i = y4lo + tid / 112, j = tid % 112;
            float acc = stage_pixel(i, j, 112, y3s, 56, sB + 3 * 1764, cw, bias);
            y4loc[(i - (b - 1)) * 112 + j] = fmaxf(acc, 0.f) * scale + shift;
        }
    }
    __syncthreads();

    // D-row dots: D[i][o] = sum_k y4loc[i][k] * gWTf[k][o], K split in 4.
    // One gWTf read feeds 3 FMAs. Garbage slots (unwritten y4loc at the grid
    // edge) produce garbage partials that the final phase never reads.
    if (tid < 896) {
        int kq = tid / 224, o = tid % 224;
        int k0 = kq * 28;
        float a0 = 0.f, a1 = 0.f, a2 = 0.f;
        for (int k = k0; k < k0 + 28; ++k) {
            float wf = gWTf[k * 224 + o];      // coalesced across o
            a0 += y4loc[k] * wf;
            a1 += y4loc[112 + k] * wf;
            a2 += y4loc[224 + k] * wf;
        }
        partial[(0 * 4 + kq) * 224 + o] = a0;
        partial[(1 * 4 + kq) * 224 + o] = a1;
        partial[(2 * 4 + kq) * 224 + o] = a2;
    }
    __syncthreads();

    // up2-y lerp of D rows + bias + sigmoid
    if (tid < 448) {
        int rr = tid / 224, o = tid % 224;
        int r = 2 * b + rr;
        float hy = clampf(((float)r + 0.5f) * 0.5f - 0.5f, 0.f, 111.f);
        int yy0 = (int)hy; float fy = hy - (float)yy0; int yy1 = min(yy0 + 1, 111);
        int s0 = yy0 - (b - 1), s1 = yy1 - (b - 1);   // always in {1,2} at edges
        float D0 = partial[(s0 * 4 + 0) * 224 + o] + partial[(s0 * 4 + 1) * 224 + o]
                 + partial[(s0 * 4 + 2) * 224 + o] + partial[(s0 * 4 + 3) * 224 + o];
        float D1 = partial[(s1 * 4 + 0) * 224 + o] + partial[(s1 * 4 + 1) * 224 + o]
                 + partial[(s1 * 4 + 2) * 224 + o] + partial[(s1 * 4 + 3) * 224 + o];
        float v = (1.f - fy) * D0 + fy * D1 + W_b[o];
        out[(size_t)r * 224 + o] = 1.f / (1.f + expf(-v));
    }
}

extern "C" void kernel_launch(void* const* d_in, const int* in_sizes, int n_in,
                              void* d_out, int out_size, void* d_ws, size_t ws_size,
                              hipStream_t stream) {
    (void)in_sizes; (void)n_in; (void)out_size; (void)ws_size;
    const float* x      = (const float*)d_in[0];
    const float* fv     = (const float*)d_in[1];
    const float* conv_w = (const float*)d_in[2];
    const float* conv_b = (const float*)d_in[3];
    const float* bng    = (const float*)d_in[4];
    const float* bnb    = (const float*)d_in[5];
    const float* bnm    = (const float*)d_in[6];
    const float* bnv    = (const float*)d_in[7];
    const float* W_w    = (const float*)d_in[8];
    const float* W_b    = (const float*)d_in[9];
    float* out = (float*)d_out;

    float* ws   = (float*)d_ws;
    float* gB   = ws;             // 7056 floats
    float* gWTf = ws + 7056;      // 25088 floats (112 x 224)

    compute_B_kernel<<<784, 256, 0, stream>>>(fv, conv_w, W_w, gB, gWTf);
    refine_kernel<<<112, 1024, 0, stream>>>(x, conv_w, conv_b, bng, bnb, bnm, bnv,
                                            W_b, gB, gWTf, out);
}